// Round 8
// baseline (1334.201 us; speedup 1.0000x reference)
//
#include <hip/hip_runtime.h>
#include <hip/hip_bf16.h>
#include <stdint.h>

typedef __bf16 bf16;
typedef __attribute__((ext_vector_type(8))) __bf16 bf16x8;
typedef __attribute__((ext_vector_type(4))) float f32x4;

#define DEVI __device__ __forceinline__

// ---------------- constants ----------------
constexpr int BATCH = 2, SEQ = 2048, HID = 1024, NHEAD = 16, HDIM = 64;
constexpr int H3 = 3072;                 // 3*HID
constexpr int MROWS = BATCH * SEQ;       // 4096
constexpr int KEXP = 9;                  // 1 (silu) + 8 spline coefs
constexpr int K1DIM = H3 * KEXP;         // 27648
constexpr int K2DIM = HID * KEXP;        // 9216

// workspace layout (bytes)
constexpr size_t WQ_OFF  = 0;
constexpr size_t AQ_OFF  = 169869312;
constexpr size_t CQ_OFF  = AQ_OFF + 226492416;
constexpr size_t QR_OFF  = CQ_OFF + 50331648;
constexpr size_t KR_OFF  = QR_OFF + 8388608;
constexpr size_t VB_OFF  = KR_OFF + 8388608;
constexpr size_t CTX_OFF = VB_OFF + 8388608;
constexpr size_t A2_OFF  = 0;
constexpr size_t W2_OFF  = 75497472;

DEVI void gld_lds16(const void* g, void* l) {
  __builtin_amdgcn_global_load_lds((const __attribute__((address_space(1))) void*)g,
                                   (__attribute__((address_space(3))) void*)l, 16, 0, 0);
}

#define WAITVM(n) asm volatile("s_waitcnt vmcnt(" #n ")" ::: "memory")
#define MEMFENCE() asm volatile("" ::: "memory")
#define BARRIER() do { __builtin_amdgcn_s_barrier(); asm volatile("" ::: "memory"); } while (0)

// silu + cubic B-spline bases on uniform grid h=0.4, knots g[j]=(j-3)*0.4-1, j=0..11
DEVI void silu_bases(float x, float* o9) {
  o9[0] = x / (1.0f + __expf(-x));
  float g[12];
#pragma unroll
  for (int j = 0; j < 12; ++j) g[j] = (float)(j - 3) * 0.4f - 1.0f;
  float b[11];
#pragma unroll
  for (int j = 0; j < 11; ++j) b[j] = (x >= g[j] && x < g[j + 1]) ? 1.0f : 0.0f;
#pragma unroll
  for (int k = 1; k <= 3; ++k) {
    const float inv = (k == 1) ? 2.5f : (k == 2) ? 1.25f : (1.0f / 1.2f);
#pragma unroll
    for (int j = 0; j + k < 11; ++j) {
      b[j] = (x - g[j]) * inv * b[j] + (g[j + k + 1] - x) * inv * b[j + 1];
    }
  }
#pragma unroll
  for (int c = 0; c < 8; ++c) o9[1 + c] = b[c];
}

// ---------------- weight repack (LDS-coalesced) ----------------
__global__ __launch_bounds__(256)
void wprep_kernel(const float* __restrict__ bw, const float* __restrict__ sw,
                  const float* __restrict__ sc, bf16* __restrict__ W, int KK) {
  __shared__ bf16 buf[256 * KEXP];
  const int tid = threadIdx.x;
  const int n = blockIdx.y;
  const int i0 = blockIdx.x * 256;
  const size_t idx = (size_t)n * KK + i0 + tid;
  float base = bw[idx];
  float scal = sc[idx];
  const float4* sp = (const float4*)(sw + idx * 8);
  float4 s0 = sp[0], s1 = sp[1];
  bf16* o = buf + tid * KEXP;
  o[0] = (bf16)base;
  o[1] = (bf16)(s0.x * scal); o[2] = (bf16)(s0.y * scal);
  o[3] = (bf16)(s0.z * scal); o[4] = (bf16)(s0.w * scal);
  o[5] = (bf16)(s1.x * scal); o[6] = (bf16)(s1.y * scal);
  o[7] = (bf16)(s1.z * scal); o[8] = (bf16)(s1.w * scal);
  __syncthreads();
  bf16* dst = W + (size_t)n * KK * KEXP + (size_t)i0 * KEXP;
#pragma unroll
  for (int j = tid; j < 256 * KEXP / 8; j += 256)
    *(bf16x8*)(dst + j * 8) = *(const bf16x8*)(buf + j * 8);
}

// ---------------- activation expansion, LDS-coalesced ----------------
__global__ __launch_bounds__(256)
void act_qkv_kernel(const float* __restrict__ qin, const float* __restrict__ kin,
                    const float* __restrict__ vin, bf16* __restrict__ A) {
  __shared__ bf16 buf[256 * KEXP];
  const int tid = threadIdx.x;
  const int m = blockIdx.y;
  const int i0 = blockIdx.x * 256;
  const int i = i0 + tid;
  const int which = i >> 10, off = i & 1023;
  const float* src = (which == 0) ? qin : (which == 1) ? kin : vin;
  float x = src[(size_t)m * HID + off];
  float o9[9];
  silu_bases(x, o9);
  bf16* o = buf + tid * KEXP;
#pragma unroll
  for (int c = 0; c < 9; ++c) o[c] = (bf16)o9[c];
  __syncthreads();
  bf16* dst = A + (size_t)m * K1DIM + (size_t)i0 * KEXP;
#pragma unroll
  for (int j = tid; j < 256 * KEXP / 8; j += 256)
    *(bf16x8*)(dst + j * 8) = *(const bf16x8*)(buf + j * 8);
}

__global__ __launch_bounds__(256)
void act_out_kernel(const float* __restrict__ ctx, bf16* __restrict__ A) {
  __shared__ bf16 buf[256 * KEXP];
  const int tid = threadIdx.x;
  const int m = blockIdx.y;
  const int i0 = blockIdx.x * 256;
  float x = ctx[(size_t)m * HID + i0 + tid];
  float o9[9];
  silu_bases(x, o9);
  bf16* o = buf + tid * KEXP;
#pragma unroll
  for (int c = 0; c < 9; ++c) o[c] = (bf16)o9[c];
  __syncthreads();
  bf16* dst = A + (size_t)m * K2DIM + (size_t)i0 * KEXP;
#pragma unroll
  for (int j = tid; j < 256 * KEXP / 8; j += 256)
    *(bf16x8*)(dst + j * 8) = *(const bf16x8*)(buf + j * 8);
}

// ---------------- bf16 GEMM: C[M][N] = A[M][K] * Bw[N][K]^T, fp32 out ----------------
// ROUND-8: counted-vmcnt pipeline RETRY with LDS within the 64KiB static limit
// (round-2/3 declared 112KiB -> kernel never launched; round-6 proved 64KiB launches).
// 128x128 tile, BK=32, THREE buffers (48KiB), stage distance 2, 1 barrier/tile,
// boundary vmcnt(4) (tile t+2's 4 loads stay in flight across the barrier).
// Ledger: prologue stages tiles 0,1 + FULL drain (order-robust). Iter t: stage
// tile t+2 into buf (t+2)%3 == (t-1)%3 (reads of it finished before end-of-(t-1)
// barrier, since MFMA consumed them); after stage, own-wave outstanding = 8
// (tiles t+1,t+2); vmcnt(4) => tile t+1 landed; barrier publishes. Tails:
// t==nt-2 -> vmcnt(0); t==nt-1 -> none.
// T2 swizzle for [.][32] rows: phys chunk c of row r holds src chunk c^((r>>1)&3);
// read phys = lq^((row>>1)&3); max 2-way bank aliasing (free). Same involution
// on pre-swizzled global source (rule #21). Line 1 (rows 64..127) shares f since
// (64+r)>>1 === r>>1 (mod 4).
__global__ __launch_bounds__(256, 3)
void gemm_kernel(const bf16* __restrict__ A, const bf16* __restrict__ Bw,
                 float* __restrict__ C, int N, int K) {
  __shared__ bf16 As[3][128 * 32];
  __shared__ bf16 Bs[3][128 * 32];
  const int tid = threadIdx.x;
  const int lane = tid & 63;
  const int l15 = lane & 15, lq = lane >> 4;
  const int wid = tid >> 6;
  const int wm = (wid >> 1) * 64, wn = (wid & 1) * 64;
  const int bm = blockIdx.y, bn = blockIdx.x;
  f32x4 acc[4][4] = {};
  // staging: thread covers row r0=tid>>2 (line 0) and 64+r0 (line 1), chunk tid&3
  const int srow = tid >> 2;
  const int schk = (tid & 3) ^ ((srow >> 1) & 3);   // pre-swizzled source chunk
  const bf16* aB = A + (size_t)(bm * 128 + srow) * K + schk * 8;
  const bf16* bB = Bw + (size_t)(bn * 128 + srow) * K + schk * 8;

  // swizzled read offsets (elements within a 128x32 buffer)
  int aoff[4], boff[4];
#pragma unroll
  for (int f = 0; f < 4; ++f) {
    int arow = wm + f * 16 + l15;
    int brow = wn + f * 16 + l15;
    aoff[f] = arow * 32 + ((lq ^ ((arow >> 1) & 3)) * 8);
    boff[f] = brow * 32 + ((lq ^ ((brow >> 1) & 3)) * 8);
  }

#define GSTAGE(bi_, kt_)                                                        \
  do {                                                                          \
    bf16* dA_ = &As[bi_][0];                                                    \
    bf16* dB_ = &Bs[bi_][0];                                                    \
    gld_lds16(aB + (kt_), dA_ + tid * 8);                                       \
    gld_lds16(aB + (size_t)64 * K + (kt_), dA_ + 2048 + tid * 8);               \
    gld_lds16(bB + (kt_), dB_ + tid * 8);                                       \
    gld_lds16(bB + (size_t)64 * K + (kt_), dB_ + 2048 + tid * 8);               \
  } while (0)

  const int nt = K >> 5;
  GSTAGE(0, 0);
  MEMFENCE();
  GSTAGE(1, (size_t)32);
  WAITVM(0);
  BARRIER();
  for (int t = 0; t < nt; ++t) {
    if (t + 2 < nt) { GSTAGE((t + 2) % 3, (size_t)(t + 2) * 32); MEMFENCE(); }
    const bf16* as = &As[t % 3][0];
    const bf16* bs = &Bs[t % 3][0];
    bf16x8 af[4], bfr[4];
#pragma unroll
    for (int mf = 0; mf < 4; ++mf) af[mf] = *(const bf16x8*)(as + aoff[mf]);
#pragma unroll
    for (int nf = 0; nf < 4; ++nf) bfr[nf] = *(const bf16x8*)(bs + boff[nf]);
    __builtin_amdgcn_s_setprio(1);
#pragma unroll
    for (int mf = 0; mf < 4; ++mf)
#pragma unroll
      for (int nf = 0; nf < 4; ++nf)
        acc[mf][nf] = __builtin_amdgcn_mfma_f32_16x16x32_bf16(af[mf], bfr[nf], acc[mf][nf], 0, 0, 0);
    __builtin_amdgcn_s_setprio(0);
    if (t < nt - 2) {
      WAITVM(4);
      BARRIER();
    } else if (t == nt - 2) {
      WAITVM(0);
      BARRIER();
    }
  }
#undef GSTAGE

#pragma unroll
  for (int mf = 0; mf < 4; ++mf)
#pragma unroll
    for (int nf = 0; nf < 4; ++nf)
#pragma unroll
      for (int r = 0; r < 4; ++r) {
        int row = bm * 128 + wm + mf * 16 + lq * 4 + r;
        int col = bn * 128 + wn + nf * 16 + l15;
        C[(size_t)row * N + col] = acc[mf][nf][r];
      }
}

// ---------------- RoPE + extract q/k/v heads to bf16 (b,h,s,d) ----------------
__global__ void rope_kernel(const float* __restrict__ Cq, bf16* __restrict__ qr,
                            bf16* __restrict__ kr, bf16* __restrict__ vb) {
  int idx = blockIdx.x * blockDim.x + threadIdx.x;  // (m, h, p)
  int p = idx & 31;
  int h = (idx >> 5) & 15;
  int m = idx >> 9;
  int s = m & (SEQ - 1);
  int b = m >> 11;
  const float* row = Cq + (size_t)m * H3 + h * 192;
  float q0 = row[2 * p], q1 = row[2 * p + 1];
  float k0 = row[64 + 2 * p], k1 = row[64 + 2 * p + 1];
  float v0 = row[128 + 2 * p], v1 = row[128 + 2 * p + 1];
  float invf = expf(-(float)p * (9.210340371976184f / 32.0f));  // 10000^(-2p/64)
  float fr = (float)s * invf;
  float sn, cs;
  sincosf(fr, &sn, &cs);
  size_t o = (((size_t)(b * NHEAD + h)) * SEQ + s) * 64 + 2 * p;
  qr[o] = (bf16)(q0 * cs - q1 * sn); qr[o + 1] = (bf16)(q1 * cs + q0 * sn);
  kr[o] = (bf16)(k0 * cs - k1 * sn); kr[o + 1] = (bf16)(k1 * cs + k0 * sn);
  vb[o] = (bf16)v0; vb[o + 1] = (bf16)v1;
}

// ---------------- flash attention: 64-row Q tile per block, 4 waves x 16 rows ----------
// Chunk-XOR swizzle on all three LDS buffers (verified round 6/7).
__global__ __launch_bounds__(256, 2)
void attn_kernel(const bf16* __restrict__ qr, const bf16* __restrict__ kr,
                 const bf16* __restrict__ vb, const float* __restrict__ mask,
                 float* __restrict__ ctx) {
  __shared__ bf16 Kt[64 * 64];       // [kv][d], chunk-swizzled
  __shared__ bf16 Vt[64 * 64];       // [d][kv] (transposed), chunk-swizzled
  __shared__ bf16 Pl[4][16 * 64];    // per-wave P tile [qrow][kv], chunk-swizzled
  const int tid = threadIdx.x, lane = tid & 63, wid = tid >> 6;
  const int l15 = lane & 15, lq = lane >> 4;
  const int qt = blockIdx.x, bh = blockIdx.y;
  const int b = bh >> 4, hh = bh & 15;
  const size_t baseQ = ((size_t)bh * SEQ + qt * 64 + wid * 16) * 64;
  bf16x8 aq[2];
  aq[0] = *(const bf16x8*)&qr[baseQ + (size_t)l15 * 64 + 0 + lq * 8];
  aq[1] = *(const bf16x8*)&qr[baseQ + (size_t)l15 * 64 + 32 + lq * 8];
  float mrow[4], lrow[4];
  f32x4 oacc[4] = {};
#pragma unroll
  for (int r = 0; r < 4; ++r) { mrow[r] = -1e30f; lrow[r] = 0.0f; }
  const float scale = 0.125f;  // 1/sqrt(64)
  const int krow = tid >> 3;
  const int kchk = (tid & 7) ^ (krow & 7);
  for (int kv0 = 0; kv0 < SEQ; kv0 += 64) {
    const bf16* kBase = kr + ((size_t)bh * SEQ + kv0 + krow) * 64 + kchk * 8;
#pragma unroll
    for (int r = 0; r < 2; ++r)
      gld_lds16(kBase + (size_t)(r * 32) * 64, Kt + r * 2048 + tid * 8);
#pragma unroll
    for (int r = 0; r < 2; ++r) {
      int row = r * 32 + (tid >> 3);   // kv index
      int c8 = (tid & 7) * 8;          // d base
      bf16x8 vv = *(const bf16x8*)&vb[((size_t)bh * SEQ + kv0 + row) * 64 + c8];
#pragma unroll
      for (int e = 0; e < 8; ++e) {
        int d = c8 + e;
        Vt[d * 64 + (((row >> 3) ^ (d & 7)) << 3) + (row & 7)] = vv[e];
      }
    }
    __syncthreads();
    // S = Q K^T
    f32x4 sacc[4] = {};
#pragma unroll
    for (int k0 = 0; k0 < 2; ++k0) {
#pragma unroll
      for (int nf = 0; nf < 4; ++nf) {
        bf16x8 bk = *(const bf16x8*)&Kt[(nf * 16 + l15) * 64 + (((k0 * 4 + lq) ^ (l15 & 7)) << 3)];
        sacc[nf] = __builtin_amdgcn_mfma_f32_16x16x32_bf16(aq[k0], bk, sacc[nf], 0, 0, 0);
      }
    }
    const int qg0 = qt * 64 + wid * 16 + lq * 4;
#pragma unroll
    for (int nf = 0; nf < 4; ++nf) {
      int kvg = kv0 + nf * 16 + l15;
#pragma unroll
      for (int r = 0; r < 4; ++r)
        sacc[nf][r] = sacc[nf][r] * scale + mask[(size_t)(qg0 + r) * SEQ + kvg];
    }
    // online softmax (row spread over 16 lanes within quarter-wave)
    float fac[4];
#pragma unroll
    for (int r = 0; r < 4; ++r) {
      float v = fmaxf(fmaxf(sacc[0][r], sacc[1][r]), fmaxf(sacc[2][r], sacc[3][r]));
      v = fmaxf(v, __shfl_xor(v, 1));
      v = fmaxf(v, __shfl_xor(v, 2));
      v = fmaxf(v, __shfl_xor(v, 4));
      v = fmaxf(v, __shfl_xor(v, 8));
      float mnew = fmaxf(mrow[r], v);
      fac[r] = __expf(mrow[r] - mnew);
      mrow[r] = mnew;
    }
    float rs[4] = {0, 0, 0, 0};
#pragma unroll
    for (int nf = 0; nf < 4; ++nf)
#pragma unroll
      for (int r = 0; r < 4; ++r) {
        float pv = __expf(sacc[nf][r] - mrow[r]);
        sacc[nf][r] = pv;
        rs[r] += pv;
      }
#pragma unroll
    for (int r = 0; r < 4; ++r) {
      float v = rs[r];
      v += __shfl_xor(v, 1); v += __shfl_xor(v, 2);
      v += __shfl_xor(v, 4); v += __shfl_xor(v, 8);
      lrow[r] = lrow[r] * fac[r] + v;
    }
    // P -> LDS (A-operand layout round trip), chunk-swizzled
#pragma unroll
    for (int nf = 0; nf < 4; ++nf)
#pragma unroll
      for (int r = 0; r < 4; ++r) {
        int qrow = lq * 4 + r;
        int col = nf * 16 + l15;
        Pl[wid][qrow * 64 + ((((col >> 3) ^ (qrow & 7))) << 3) + (col & 7)] = (bf16)sacc[nf][r];
      }
    // rescale O
#pragma unroll
    for (int nf = 0; nf < 4; ++nf)
#pragma unroll
      for (int r = 0; r < 4; ++r)
        oacc[nf][r] *= fac[r];
    // O += P V
#pragma unroll
    for (int k0 = 0; k0 < 2; ++k0) {
      bf16x8 ap = *(const bf16x8*)&Pl[wid][l15 * 64 + (((k0 * 4 + lq) ^ (l15 & 7)) << 3)];
#pragma unroll
      for (int nf = 0; nf < 4; ++nf) {
        bf16x8 bv = *(const bf16x8*)&Vt[(nf * 16 + l15) * 64 + (((k0 * 4 + lq) ^ (l15 & 7)) << 3)];
        oacc[nf] = __builtin_amdgcn_mfma_f32_16x16x32_bf16(ap, bv, oacc[nf], 0, 0, 0);
      }
    }
    __syncthreads();
  }
#pragma unroll
  for (int nf = 0; nf < 4; ++nf)
#pragma unroll
    for (int r = 0; r < 4; ++r) {
      int row = qt * 64 + wid * 16 + lq * 4 + r;
      int col = hh * 64 + nf * 16 + l15;
      ctx[((size_t)b * SEQ + row) * HID + col] = oacc[nf][r] / lrow[r];
    }
}

// ---------------- launch ----------------
extern "C" void kernel_launch(void* const* d_in, const int* in_sizes, int n_in,
                              void* d_out, int out_size, void* d_ws, size_t ws_size,
                              hipStream_t stream) {
  const float* qin    = (const float*)d_in[0];
  const float* kin    = (const float*)d_in[1];
  const float* vin    = (const float*)d_in[2];
  const float* mask   = (const float*)d_in[3];
  const float* qkv_bw = (const float*)d_in[4];
  const float* qkv_sw = (const float*)d_in[5];
  const float* qkv_sc = (const float*)d_in[6];
  const float* out_bw = (const float*)d_in[7];
  const float* out_sw = (const float*)d_in[8];
  const float* out_sc = (const float*)d_in[9];
  char* ws = (char*)d_ws;
  bf16* Wq  = (bf16*)(ws + WQ_OFF);
  bf16* Aq  = (bf16*)(ws + AQ_OFF);
  float* Cq = (float*)(ws + CQ_OFF);
  bf16* qr  = (bf16*)(ws + QR_OFF);
  bf16* kr  = (bf16*)(ws + KR_OFF);
  bf16* vb  = (bf16*)(ws + VB_OFF);
  float* ctx = (float*)(ws + CTX_OFF);
  bf16* A2  = (bf16*)(ws + A2_OFF);
  bf16* W2  = (bf16*)(ws + W2_OFF);

  wprep_kernel<<<dim3(H3 / 256, H3), 256, 0, stream>>>(qkv_bw, qkv_sw, qkv_sc, Wq, H3);
  act_qkv_kernel<<<dim3(H3 / 256, MROWS), 256, 0, stream>>>(qin, kin, vin, Aq);
  gemm_kernel<<<dim3(H3 / 128, MROWS / 128), 256, 0, stream>>>(Aq, Wq, Cq, H3, K1DIM);
  rope_kernel<<<(MROWS * NHEAD * 32) / 256, 256, 0, stream>>>(Cq, qr, kr, vb);
  attn_kernel<<<dim3(SEQ / 64, BATCH * NHEAD), 256, 0, stream>>>(qr, kr, vb, mask, ctx);
  act_out_kernel<<<dim3(HID / 256, MROWS), 256, 0, stream>>>(ctx, A2);
  wprep_kernel<<<dim3(HID / 256, HID), 256, 0, stream>>>(out_bw, out_sw, out_sc, W2, HID);
  gemm_kernel<<<dim3(HID / 128, MROWS / 128), 256, 0, stream>>>(A2, W2, (float*)d_out, HID, K2DIM);
}

// Round 9
// 1150.500 us; speedup vs baseline: 1.1597x; 1.1597x over previous
//
#include <hip/hip_runtime.h>
#include <hip/hip_bf16.h>
#include <stdint.h>

typedef __bf16 bf16;
typedef __attribute__((ext_vector_type(8))) __bf16 bf16x8;
typedef __attribute__((ext_vector_type(4))) float f32x4;

#define DEVI __device__ __forceinline__

// ---------------- constants ----------------
constexpr int BATCH = 2, SEQ = 2048, HID = 1024, NHEAD = 16, HDIM = 64;
constexpr int H3 = 3072;                 // 3*HID
constexpr int MROWS = BATCH * SEQ;       // 4096
constexpr int KEXP = 9;                  // 1 (silu) + 8 spline coefs
constexpr int K1DIM = H3 * KEXP;         // 27648
constexpr int K2DIM = HID * KEXP;        // 9216

// workspace layout (bytes)
constexpr size_t WQ_OFF  = 0;
constexpr size_t AQ_OFF  = 169869312;
constexpr size_t CQ_OFF  = AQ_OFF + 226492416;
constexpr size_t QR_OFF  = CQ_OFF + 50331648;
constexpr size_t KR_OFF  = QR_OFF + 8388608;
constexpr size_t VB_OFF  = KR_OFF + 8388608;
constexpr size_t CTX_OFF = VB_OFF + 8388608;
constexpr size_t A2_OFF  = 0;
constexpr size_t W2_OFF  = 75497472;

DEVI void gld_lds16(const void* g, void* l) {
  __builtin_amdgcn_global_load_lds((const __attribute__((address_space(1))) void*)g,
                                   (__attribute__((address_space(3))) void*)l, 16, 0, 0);
}

#define WAITVM0() asm volatile("s_waitcnt vmcnt(0)" ::: "memory")
#define MEMFENCE() asm volatile("" ::: "memory")
#define BARRIER() do { __builtin_amdgcn_s_barrier(); asm volatile("" ::: "memory"); } while (0)

// silu + cubic B-spline bases on uniform grid h=0.4, knots g[j]=(j-3)*0.4-1, j=0..11
DEVI void silu_bases(float x, float* o9) {
  o9[0] = x / (1.0f + __expf(-x));
  float g[12];
#pragma unroll
  for (int j = 0; j < 12; ++j) g[j] = (float)(j - 3) * 0.4f - 1.0f;
  float b[11];
#pragma unroll
  for (int j = 0; j < 11; ++j) b[j] = (x >= g[j] && x < g[j + 1]) ? 1.0f : 0.0f;
#pragma unroll
  for (int k = 1; k <= 3; ++k) {
    const float inv = (k == 1) ? 2.5f : (k == 2) ? 1.25f : (1.0f / 1.2f);
#pragma unroll
    for (int j = 0; j + k < 11; ++j) {
      b[j] = (x - g[j]) * inv * b[j] + (g[j + k + 1] - x) * inv * b[j + 1];
    }
  }
#pragma unroll
  for (int c = 0; c < 8; ++c) o9[1 + c] = b[c];
}

// ---------------- weight repack (LDS-coalesced) ----------------
__global__ __launch_bounds__(256)
void wprep_kernel(const float* __restrict__ bw, const float* __restrict__ sw,
                  const float* __restrict__ sc, bf16* __restrict__ W, int KK) {
  __shared__ bf16 buf[256 * KEXP];
  const int tid = threadIdx.x;
  const int n = blockIdx.y;
  const int i0 = blockIdx.x * 256;
  const size_t idx = (size_t)n * KK + i0 + tid;
  float base = bw[idx];
  float scal = sc[idx];
  const float4* sp = (const float4*)(sw + idx * 8);
  float4 s0 = sp[0], s1 = sp[1];
  bf16* o = buf + tid * KEXP;
  o[0] = (bf16)base;
  o[1] = (bf16)(s0.x * scal); o[2] = (bf16)(s0.y * scal);
  o[3] = (bf16)(s0.z * scal); o[4] = (bf16)(s0.w * scal);
  o[5] = (bf16)(s1.x * scal); o[6] = (bf16)(s1.y * scal);
  o[7] = (bf16)(s1.z * scal); o[8] = (bf16)(s1.w * scal);
  __syncthreads();
  bf16* dst = W + (size_t)n * KK * KEXP + (size_t)i0 * KEXP;
#pragma unroll
  for (int j = tid; j < 256 * KEXP / 8; j += 256)
    *(bf16x8*)(dst + j * 8) = *(const bf16x8*)(buf + j * 8);
}

// ---------------- activation expansion, LDS-coalesced ----------------
__global__ __launch_bounds__(256)
void act_qkv_kernel(const float* __restrict__ qin, const float* __restrict__ kin,
                    const float* __restrict__ vin, bf16* __restrict__ A) {
  __shared__ bf16 buf[256 * KEXP];
  const int tid = threadIdx.x;
  const int m = blockIdx.y;
  const int i0 = blockIdx.x * 256;
  const int i = i0 + tid;
  const int which = i >> 10, off = i & 1023;
  const float* src = (which == 0) ? qin : (which == 1) ? kin : vin;
  float x = src[(size_t)m * HID + off];
  float o9[9];
  silu_bases(x, o9);
  bf16* o = buf + tid * KEXP;
#pragma unroll
  for (int c = 0; c < 9; ++c) o[c] = (bf16)o9[c];
  __syncthreads();
  bf16* dst = A + (size_t)m * K1DIM + (size_t)i0 * KEXP;
#pragma unroll
  for (int j = tid; j < 256 * KEXP / 8; j += 256)
    *(bf16x8*)(dst + j * 8) = *(const bf16x8*)(buf + j * 8);
}

__global__ __launch_bounds__(256)
void act_out_kernel(const float* __restrict__ ctx, bf16* __restrict__ A) {
  __shared__ bf16 buf[256 * KEXP];
  const int tid = threadIdx.x;
  const int m = blockIdx.y;
  const int i0 = blockIdx.x * 256;
  float x = ctx[(size_t)m * HID + i0 + tid];
  float o9[9];
  silu_bases(x, o9);
  bf16* o = buf + tid * KEXP;
#pragma unroll
  for (int c = 0; c < 9; ++c) o[c] = (bf16)o9[c];
  __syncthreads();
  bf16* dst = A + (size_t)m * K2DIM + (size_t)i0 * KEXP;
#pragma unroll
  for (int j = tid; j < 256 * KEXP / 8; j += 256)
    *(bf16x8*)(dst + j * 8) = *(const bf16x8*)(buf + j * 8);
}

// ---------------- bf16 GEMM: C[M][N] = A[M][K] * Bw[N][K]^T, fp32 out ----------------
// ROUND-4 EXACT CONFIG (measured best: 690-695us, MfmaUtil 45%, conflicts 0).
// Round-8 showed counted-vmcnt BK=32 pipeline is correct but SLOWER (850us:
// halved MFMA-per-barrier + per-iter overhead dominate). 2-phase + grid-resident
// overlap is the 128^2 structural optimum; do not touch without the full 256^2
// 8-phase template.
__global__ __launch_bounds__(256, 2)
void gemm_kernel(const bf16* __restrict__ A, const bf16* __restrict__ Bw,
                 float* __restrict__ C, int N, int K) {
  __shared__ bf16 As[128 * 64];
  __shared__ bf16 Bs[128 * 64];
  const int tid = threadIdx.x;
  const int lane = tid & 63;
  const int l15 = lane & 15, lq = lane >> 4;
  const int wid = tid >> 6;
  const int wm = (wid >> 1) * 64, wn = (wid & 1) * 64;
  const int bm = blockIdx.y, bn = blockIdx.x;
  f32x4 acc[4][4] = {};
  const int srow = tid >> 3;                         // staged row within 32-row line
  const int schk = (tid & 7) ^ (srow & 7);           // pre-swizzled source chunk
  const bf16* aB = A + (size_t)(bm * 128 + srow) * K + schk * 8;
  const bf16* bB = Bw + (size_t)(bn * 128 + srow) * K + schk * 8;

  // precompute swizzled read offsets (elements)
  int aoff[2][4], boff[2][4];
#pragma unroll
  for (int ks = 0; ks < 2; ++ks) {
#pragma unroll
    for (int f = 0; f < 4; ++f) {
      int arow = wm + f * 16 + l15;
      int brow = wn + f * 16 + l15;
      aoff[ks][f] = arow * 64 + (((ks * 4 + lq) ^ (arow & 7)) * 8);
      boff[ks][f] = brow * 64 + (((ks * 4 + lq) ^ (brow & 7)) * 8);
    }
  }

  for (int kt = 0; kt < K; kt += 64) {
#pragma unroll
    for (int r = 0; r < 4; ++r) {
      gld_lds16(aB + (size_t)(r * 32) * K + kt, As + r * 2048 + tid * 8);
      gld_lds16(bB + (size_t)(r * 32) * K + kt, Bs + r * 2048 + tid * 8);
    }
    __syncthreads();
#pragma unroll
    for (int ks = 0; ks < 2; ++ks) {
      bf16x8 af[4], bfr[4];
#pragma unroll
      for (int mf = 0; mf < 4; ++mf)
        af[mf] = *(const bf16x8*)&As[aoff[ks][mf]];
#pragma unroll
      for (int nf = 0; nf < 4; ++nf)
        bfr[nf] = *(const bf16x8*)&Bs[boff[ks][nf]];
#pragma unroll
      for (int mf = 0; mf < 4; ++mf)
#pragma unroll
        for (int nf = 0; nf < 4; ++nf)
          acc[mf][nf] = __builtin_amdgcn_mfma_f32_16x16x32_bf16(af[mf], bfr[nf], acc[mf][nf], 0, 0, 0);
    }
    __syncthreads();
  }
#pragma unroll
  for (int mf = 0; mf < 4; ++mf)
#pragma unroll
    for (int nf = 0; nf < 4; ++nf)
#pragma unroll
      for (int r = 0; r < 4; ++r) {
        int row = bm * 128 + wm + mf * 16 + lq * 4 + r;
        int col = bn * 128 + wn + nf * 16 + l15;
        C[(size_t)row * N + col] = acc[mf][nf][r];
      }
}

// ---------------- RoPE + extract heads ----------------
// q pre-scaled by 1/sqrt(64); V written TRANSPOSED per head: vt[(bh*64+d)*SEQ + s]
// (so attn can stage V^T with coalesced global_load_lds instead of LDS scatter).
__global__ void rope_kernel(const float* __restrict__ Cq, bf16* __restrict__ qr,
                            bf16* __restrict__ kr, bf16* __restrict__ vt) {
  int idx = blockIdx.x * blockDim.x + threadIdx.x;  // (m, h, p)
  int p = idx & 31;
  int h = (idx >> 5) & 15;
  int m = idx >> 9;
  int s = m & (SEQ - 1);
  int b = m >> 11;
  const float* row = Cq + (size_t)m * H3 + h * 192;
  float q0 = row[2 * p], q1 = row[2 * p + 1];
  float k0 = row[64 + 2 * p], k1 = row[64 + 2 * p + 1];
  float v0 = row[128 + 2 * p], v1 = row[128 + 2 * p + 1];
  float invf = expf(-(float)p * (9.210340371976184f / 32.0f));  // 10000^(-2p/64)
  float fr = (float)s * invf;
  float sn, cs;
  sincosf(fr, &sn, &cs);
  const int bh = b * NHEAD + h;
  size_t o = ((size_t)bh * SEQ + s) * 64 + 2 * p;
  qr[o] = (bf16)((q0 * cs - q1 * sn) * 0.125f);
  qr[o + 1] = (bf16)((q1 * cs + q0 * sn) * 0.125f);
  kr[o] = (bf16)(k0 * cs - k1 * sn); kr[o + 1] = (bf16)(k1 * cs + k0 * sn);
  vt[((size_t)bh * 64 + 2 * p) * SEQ + s] = (bf16)v0;
  vt[((size_t)bh * 64 + 2 * p + 1) * SEQ + s] = (bf16)v1;
}

// ---------------- flash attention: 64-row Q tile per block, 4 waves x 16 rows ----------
// ROUND-9: K and V^T both staged via global_load_lds (pre-swizzled source, verified
// pattern); double-buffered with issue-early staging (stage t+1 at top of compute t,
// vmcnt(0)+barrier at tile end waits on ~800-cycle-old loads => hidden); ONE barrier
// per tile. Q pre-scaled in rope. Pl round-trip unchanged (verified).
__global__ __launch_bounds__(256, 2)
void attn_kernel(const bf16* __restrict__ qr, const bf16* __restrict__ kr,
                 const bf16* __restrict__ vt, const float* __restrict__ mask,
                 float* __restrict__ ctx) {
  __shared__ bf16 Kt[2][64 * 64];    // [kv][d], chunk-swizzled
  __shared__ bf16 Vt[2][64 * 64];    // [d][kv], chunk-swizzled
  __shared__ bf16 Pl[4][16 * 64];    // per-wave P tile [qrow][kv], chunk-swizzled
  const int tid = threadIdx.x, lane = tid & 63, wid = tid >> 6;
  const int l15 = lane & 15, lq = lane >> 4;
  const int qt = blockIdx.x, bh = blockIdx.y;
  const int b = bh >> 4, hh = bh & 15;
  const size_t baseQ = ((size_t)bh * SEQ + qt * 64 + wid * 16) * 64;
  bf16x8 aq[2];
  aq[0] = *(const bf16x8*)&qr[baseQ + (size_t)l15 * 64 + 0 + lq * 8];
  aq[1] = *(const bf16x8*)&qr[baseQ + (size_t)l15 * 64 + 32 + lq * 8];
  float mrow[4], lrow[4];
  f32x4 oacc[4] = {};
#pragma unroll
  for (int r = 0; r < 4; ++r) { mrow[r] = -1e30f; lrow[r] = 0.0f; }
  const int srow = tid >> 3;                    // row within 32-row line
  const int schk = (tid & 7) ^ (srow & 7);      // pre-swizzled source chunk
  const bf16* kBase = kr + ((size_t)bh * SEQ + srow) * 64 + schk * 8;
  const bf16* vBase = vt + ((size_t)bh * 64 + srow) * SEQ + schk * 8;

#define ASTAGE(bi_, kv_)                                                        \
  do {                                                                          \
    gld_lds16(kBase + (size_t)(kv_) * 64, &Kt[bi_][0] + tid * 8);               \
    gld_lds16(kBase + (size_t)((kv_) + 32) * 64, &Kt[bi_][0] + 2048 + tid * 8); \
    gld_lds16(vBase + (kv_), &Vt[bi_][0] + tid * 8);                            \
    gld_lds16(vBase + (size_t)32 * SEQ + (kv_), &Vt[bi_][0] + 2048 + tid * 8);  \
  } while (0)

  ASTAGE(0, 0);
  WAITVM0();
  BARRIER();
  for (int kv0 = 0; kv0 < SEQ; kv0 += 64) {
    const int cur = (kv0 >> 6) & 1;
    if (kv0 + 64 < SEQ) { ASTAGE(cur ^ 1, kv0 + 64); MEMFENCE(); }
    const bf16* kt = &Kt[cur][0];
    const bf16* vtl = &Vt[cur][0];
    // S = Q K^T   (q pre-scaled by 1/8)
    f32x4 sacc[4] = {};
#pragma unroll
    for (int k0 = 0; k0 < 2; ++k0) {
#pragma unroll
      for (int nf = 0; nf < 4; ++nf) {
        bf16x8 bk = *(const bf16x8*)&kt[(nf * 16 + l15) * 64 + (((k0 * 4 + lq) ^ (l15 & 7)) << 3)];
        sacc[nf] = __builtin_amdgcn_mfma_f32_16x16x32_bf16(aq[k0], bk, sacc[nf], 0, 0, 0);
      }
    }
    const int qg0 = qt * 64 + wid * 16 + lq * 4;
#pragma unroll
    for (int nf = 0; nf < 4; ++nf) {
      int kvg = kv0 + nf * 16 + l15;
#pragma unroll
      for (int r = 0; r < 4; ++r)
        sacc[nf][r] += mask[(size_t)(qg0 + r) * SEQ + kvg];
    }
    // online softmax (row spread over 16 lanes within quarter-wave)
    float fac[4];
#pragma unroll
    for (int r = 0; r < 4; ++r) {
      float v = fmaxf(fmaxf(sacc[0][r], sacc[1][r]), fmaxf(sacc[2][r], sacc[3][r]));
      v = fmaxf(v, __shfl_xor(v, 1));
      v = fmaxf(v, __shfl_xor(v, 2));
      v = fmaxf(v, __shfl_xor(v, 4));
      v = fmaxf(v, __shfl_xor(v, 8));
      float mnew = fmaxf(mrow[r], v);
      fac[r] = __expf(mrow[r] - mnew);
      mrow[r] = mnew;
    }
    float rs[4] = {0, 0, 0, 0};
#pragma unroll
    for (int nf = 0; nf < 4; ++nf)
#pragma unroll
      for (int r = 0; r < 4; ++r) {
        float pv = __expf(sacc[nf][r] - mrow[r]);
        sacc[nf][r] = pv;
        rs[r] += pv;
      }
#pragma unroll
    for (int r = 0; r < 4; ++r) {
      float v = rs[r];
      v += __shfl_xor(v, 1); v += __shfl_xor(v, 2);
      v += __shfl_xor(v, 4); v += __shfl_xor(v, 8);
      lrow[r] = lrow[r] * fac[r] + v;
    }
    // P -> LDS (A-operand layout round trip), chunk-swizzled (wave-private)
#pragma unroll
    for (int nf = 0; nf < 4; ++nf)
#pragma unroll
      for (int r = 0; r < 4; ++r) {
        int qrow = lq * 4 + r;
        int col = nf * 16 + l15;
        Pl[wid][qrow * 64 + ((((col >> 3) ^ (qrow & 7))) << 3) + (col & 7)] = (bf16)sacc[nf][r];
      }
    // rescale O
#pragma unroll
    for (int nf = 0; nf < 4; ++nf)
#pragma unroll
      for (int r = 0; r < 4; ++r)
        oacc[nf][r] *= fac[r];
    // O += P V
#pragma unroll
    for (int k0 = 0; k0 < 2; ++k0) {
      bf16x8 ap = *(const bf16x8*)&Pl[wid][l15 * 64 + (((k0 * 4 + lq) ^ (l15 & 7)) << 3)];
#pragma unroll
      for (int nf = 0; nf < 4; ++nf) {
        bf16x8 bv = *(const bf16x8*)&vtl[(nf * 16 + l15) * 64 + (((k0 * 4 + lq) ^ (l15 & 7)) << 3)];
        oacc[nf] = __builtin_amdgcn_mfma_f32_16x16x32_bf16(ap, bv, oacc[nf], 0, 0, 0);
      }
    }
    WAITVM0();
    BARRIER();
  }
#undef ASTAGE
#pragma unroll
  for (int nf = 0; nf < 4; ++nf)
#pragma unroll
    for (int r = 0; r < 4; ++r) {
      int row = qt * 64 + wid * 16 + lq * 4 + r;
      int col = hh * 64 + nf * 16 + l15;
      ctx[((size_t)b * SEQ + row) * HID + col] = oacc[nf][r] / lrow[r];
    }
}

// ---------------- launch ----------------
extern "C" void kernel_launch(void* const* d_in, const int* in_sizes, int n_in,
                              void* d_out, int out_size, void* d_ws, size_t ws_size,
                              hipStream_t stream) {
  const float* qin    = (const float*)d_in[0];
  const float* kin    = (const float*)d_in[1];
  const float* vin    = (const float*)d_in[2];
  const float* mask   = (const float*)d_in[3];
  const float* qkv_bw = (const float*)d_in[4];
  const float* qkv_sw = (const float*)d_in[5];
  const float* qkv_sc = (const float*)d_in[6];
  const float* out_bw = (const float*)d_in[7];
  const float* out_sw = (const float*)d_in[8];
  const float* out_sc = (const float*)d_in[9];
  char* ws = (char*)d_ws;
  bf16* Wq  = (bf16*)(ws + WQ_OFF);
  bf16* Aq  = (bf16*)(ws + AQ_OFF);
  float* Cq = (float*)(ws + CQ_OFF);
  bf16* qr  = (bf16*)(ws + QR_OFF);
  bf16* kr  = (bf16*)(ws + KR_OFF);
  bf16* vt  = (bf16*)(ws + VB_OFF);
  float* ctx = (float*)(ws + CTX_OFF);
  bf16* A2  = (bf16*)(ws + A2_OFF);
  bf16* W2  = (bf16*)(ws + W2_OFF);

  wprep_kernel<<<dim3(H3 / 256, H3), 256, 0, stream>>>(qkv_bw, qkv_sw, qkv_sc, Wq, H3);
  act_qkv_kernel<<<dim3(H3 / 256, MROWS), 256, 0, stream>>>(qin, kin, vin, Aq);
  gemm_kernel<<<dim3(H3 / 128, MROWS / 128), 256, 0, stream>>>(Aq, Wq, Cq, H3, K1DIM);
  rope_kernel<<<(MROWS * NHEAD * 32) / 256, 256, 0, stream>>>(Cq, qr, kr, vt);
  attn_kernel<<<dim3(SEQ / 64, BATCH * NHEAD), 256, 0, stream>>>(qr, kr, vt, mask, ctx);
  act_out_kernel<<<dim3(HID / 256, MROWS), 256, 0, stream>>>(ctx, A2);
  wprep_kernel<<<dim3(HID / 256, HID), 256, 0, stream>>>(out_bw, out_sw, out_sc, W2, HID);
  gemm_kernel<<<dim3(HID / 128, MROWS / 128), 256, 0, stream>>>(A2, W2, (float*)d_out, HID, K2DIM);
}

// Round 10
// 1118.524 us; speedup vs baseline: 1.1928x; 1.0286x over previous
//
#include <hip/hip_runtime.h>
#include <hip/hip_bf16.h>
#include <stdint.h>

typedef __bf16 bf16;
typedef __attribute__((ext_vector_type(4))) __bf16 bf16x4;
typedef __attribute__((ext_vector_type(8))) __bf16 bf16x8;
typedef __attribute__((ext_vector_type(4))) float f32x4;

#define DEVI __device__ __forceinline__

// ---------------- constants ----------------
constexpr int BATCH = 2, SEQ = 2048, HID = 1024, NHEAD = 16, HDIM = 64;
constexpr int H3 = 3072;                 // 3*HID
constexpr int MROWS = BATCH * SEQ;       // 4096
constexpr int KEXP = 9;                  // 1 (silu) + 8 spline coefs
constexpr int K1DIM = H3 * KEXP;         // 27648
constexpr int K2DIM = HID * KEXP;        // 9216

// workspace layout (bytes)
constexpr size_t WQ_OFF  = 0;
constexpr size_t AQ_OFF  = 169869312;
constexpr size_t CQ_OFF  = AQ_OFF + 226492416;
constexpr size_t QR_OFF  = CQ_OFF + 50331648;
constexpr size_t KR_OFF  = QR_OFF + 8388608;
constexpr size_t VB_OFF  = KR_OFF + 8388608;
constexpr size_t CTX_OFF = VB_OFF + 8388608;
constexpr size_t A2_OFF  = 0;                       // reuse Wq region (dead after gemm1)
constexpr size_t W2_OFF  = 75497472;
constexpr size_t MB_OFF  = W2_OFF + 18874368;       // bf16 mask (8.4MB), still in dead-Wq region

DEVI void gld_lds16(const void* g, void* l) {
  __builtin_amdgcn_global_load_lds((const __attribute__((address_space(1))) void*)g,
                                   (__attribute__((address_space(3))) void*)l, 16, 0, 0);
}

#define WAITVM0() asm volatile("s_waitcnt vmcnt(0)" ::: "memory")
#define MEMFENCE() asm volatile("" ::: "memory")
#define BARRIER() do { __builtin_amdgcn_s_barrier(); asm volatile("" ::: "memory"); } while (0)

// silu + cubic B-spline bases on uniform grid h=0.4, knots g[j]=(j-3)*0.4-1, j=0..11
DEVI void silu_bases(float x, float* o9) {
  o9[0] = x / (1.0f + __expf(-x));
  float g[12];
#pragma unroll
  for (int j = 0; j < 12; ++j) g[j] = (float)(j - 3) * 0.4f - 1.0f;
  float b[11];
#pragma unroll
  for (int j = 0; j < 11; ++j) b[j] = (x >= g[j] && x < g[j + 1]) ? 1.0f : 0.0f;
#pragma unroll
  for (int k = 1; k <= 3; ++k) {
    const float inv = (k == 1) ? 2.5f : (k == 2) ? 1.25f : (1.0f / 1.2f);
#pragma unroll
    for (int j = 0; j + k < 11; ++j) {
      b[j] = (x - g[j]) * inv * b[j] + (g[j + k + 1] - x) * inv * b[j + 1];
    }
  }
#pragma unroll
  for (int c = 0; c < 8; ++c) o9[1 + c] = b[c];
}

// ---------------- weight repack (LDS-coalesced) ----------------
__global__ __launch_bounds__(256)
void wprep_kernel(const float* __restrict__ bw, const float* __restrict__ sw,
                  const float* __restrict__ sc, bf16* __restrict__ W, int KK) {
  __shared__ bf16 buf[256 * KEXP];
  const int tid = threadIdx.x;
  const int n = blockIdx.y;
  const int i0 = blockIdx.x * 256;
  const size_t idx = (size_t)n * KK + i0 + tid;
  float base = bw[idx];
  float scal = sc[idx];
  const float4* sp = (const float4*)(sw + idx * 8);
  float4 s0 = sp[0], s1 = sp[1];
  bf16* o = buf + tid * KEXP;
  o[0] = (bf16)base;
  o[1] = (bf16)(s0.x * scal); o[2] = (bf16)(s0.y * scal);
  o[3] = (bf16)(s0.z * scal); o[4] = (bf16)(s0.w * scal);
  o[5] = (bf16)(s1.x * scal); o[6] = (bf16)(s1.y * scal);
  o[7] = (bf16)(s1.z * scal); o[8] = (bf16)(s1.w * scal);
  __syncthreads();
  bf16* dst = W + (size_t)n * KK * KEXP + (size_t)i0 * KEXP;
#pragma unroll
  for (int j = tid; j < 256 * KEXP / 8; j += 256)
    *(bf16x8*)(dst + j * 8) = *(const bf16x8*)(buf + j * 8);
}

// ---------------- activation expansion, LDS-coalesced ----------------
__global__ __launch_bounds__(256)
void act_qkv_kernel(const float* __restrict__ qin, const float* __restrict__ kin,
                    const float* __restrict__ vin, bf16* __restrict__ A) {
  __shared__ bf16 buf[256 * KEXP];
  const int tid = threadIdx.x;
  const int m = blockIdx.y;
  const int i0 = blockIdx.x * 256;
  const int i = i0 + tid;
  const int which = i >> 10, off = i & 1023;
  const float* src = (which == 0) ? qin : (which == 1) ? kin : vin;
  float x = src[(size_t)m * HID + off];
  float o9[9];
  silu_bases(x, o9);
  bf16* o = buf + tid * KEXP;
#pragma unroll
  for (int c = 0; c < 9; ++c) o[c] = (bf16)o9[c];
  __syncthreads();
  bf16* dst = A + (size_t)m * K1DIM + (size_t)i0 * KEXP;
#pragma unroll
  for (int j = tid; j < 256 * KEXP / 8; j += 256)
    *(bf16x8*)(dst + j * 8) = *(const bf16x8*)(buf + j * 8);
}

__global__ __launch_bounds__(256)
void act_out_kernel(const float* __restrict__ ctx, bf16* __restrict__ A) {
  __shared__ bf16 buf[256 * KEXP];
  const int tid = threadIdx.x;
  const int m = blockIdx.y;
  const int i0 = blockIdx.x * 256;
  float x = ctx[(size_t)m * HID + i0 + tid];
  float o9[9];
  silu_bases(x, o9);
  bf16* o = buf + tid * KEXP;
#pragma unroll
  for (int c = 0; c < 9; ++c) o[c] = (bf16)o9[c];
  __syncthreads();
  bf16* dst = A + (size_t)m * K2DIM + (size_t)i0 * KEXP;
#pragma unroll
  for (int j = tid; j < 256 * KEXP / 8; j += 256)
    *(bf16x8*)(dst + j * 8) = *(const bf16x8*)(buf + j * 8);
}

// ---------------- mask fp32 -> bf16 (read 32x by attn; halve the stream) ----------------
__global__ __launch_bounds__(256)
void maskprep_kernel(const float* __restrict__ m, bf16* __restrict__ mb) {
  int i = (blockIdx.x * 256 + threadIdx.x) * 4;
  float4 v = *(const float4*)(m + i);
  bf16x4 o = { (bf16)v.x, (bf16)v.y, (bf16)v.z, (bf16)v.w };
  *(bf16x4*)(mb + i) = o;
}

// ---------------- gemm1: 128x128 tile (ROUND-4 EXACT CONFIG, measured best) ----------
__global__ __launch_bounds__(256, 2)
void gemm_kernel(const bf16* __restrict__ A, const bf16* __restrict__ Bw,
                 float* __restrict__ C, int N, int K) {
  __shared__ bf16 As[128 * 64];
  __shared__ bf16 Bs[128 * 64];
  const int tid = threadIdx.x;
  const int lane = tid & 63;
  const int l15 = lane & 15, lq = lane >> 4;
  const int wid = tid >> 6;
  const int wm = (wid >> 1) * 64, wn = (wid & 1) * 64;
  const int bm = blockIdx.y, bn = blockIdx.x;
  f32x4 acc[4][4] = {};
  const int srow = tid >> 3;
  const int schk = (tid & 7) ^ (srow & 7);
  const bf16* aB = A + (size_t)(bm * 128 + srow) * K + schk * 8;
  const bf16* bB = Bw + (size_t)(bn * 128 + srow) * K + schk * 8;

  int aoff[2][4], boff[2][4];
#pragma unroll
  for (int ks = 0; ks < 2; ++ks) {
#pragma unroll
    for (int f = 0; f < 4; ++f) {
      int arow = wm + f * 16 + l15;
      int brow = wn + f * 16 + l15;
      aoff[ks][f] = arow * 64 + (((ks * 4 + lq) ^ (arow & 7)) * 8);
      boff[ks][f] = brow * 64 + (((ks * 4 + lq) ^ (brow & 7)) * 8);
    }
  }

  for (int kt = 0; kt < K; kt += 64) {
#pragma unroll
    for (int r = 0; r < 4; ++r) {
      gld_lds16(aB + (size_t)(r * 32) * K + kt, As + r * 2048 + tid * 8);
      gld_lds16(bB + (size_t)(r * 32) * K + kt, Bs + r * 2048 + tid * 8);
    }
    __syncthreads();
#pragma unroll
    for (int ks = 0; ks < 2; ++ks) {
      bf16x8 af[4], bfr[4];
#pragma unroll
      for (int mf = 0; mf < 4; ++mf)
        af[mf] = *(const bf16x8*)&As[aoff[ks][mf]];
#pragma unroll
      for (int nf = 0; nf < 4; ++nf)
        bfr[nf] = *(const bf16x8*)&Bs[boff[ks][nf]];
#pragma unroll
      for (int mf = 0; mf < 4; ++mf)
#pragma unroll
        for (int nf = 0; nf < 4; ++nf)
          acc[mf][nf] = __builtin_amdgcn_mfma_f32_16x16x32_bf16(af[mf], bfr[nf], acc[mf][nf], 0, 0, 0);
    }
    __syncthreads();
  }
#pragma unroll
  for (int mf = 0; mf < 4; ++mf)
#pragma unroll
    for (int nf = 0; nf < 4; ++nf)
#pragma unroll
      for (int r = 0; r < 4; ++r) {
        int row = bm * 128 + wm + mf * 16 + lq * 4 + r;
        int col = bn * 128 + wn + nf * 16 + l15;
        C[(size_t)row * N + col] = acc[mf][nf][r];
      }
}

// ---------------- gemm2: 64x128 tile -> grid 8x64 = 512 blocks = 2/CU ----------------
// (old 128x128 at N=1024 gave 256 blocks = 1/CU: round-6-style occupancy collapse.)
// Same verified 2-phase skeleton + swizzle family; 2x2 waves of 32x64.
__global__ __launch_bounds__(256, 2)
void gemm2_kernel(const bf16* __restrict__ A, const bf16* __restrict__ Bw,
                  float* __restrict__ C, int N, int K) {
  __shared__ bf16 As[64 * 64];       // 8 KiB
  __shared__ bf16 Bs[128 * 64];      // 16 KiB
  const int tid = threadIdx.x;
  const int lane = tid & 63;
  const int l15 = lane & 15, lq = lane >> 4;
  const int wid = tid >> 6;
  const int wr = wid >> 1, wc = wid & 1;   // wave tile 32(M) x 64(N)
  const int bm = blockIdx.y, bn = blockIdx.x;
  f32x4 acc[2][4] = {};
  const int srow = tid >> 3;
  const int schk = (tid & 7) ^ (srow & 7);
  const bf16* aB = A + (size_t)(bm * 64 + srow) * K + schk * 8;
  const bf16* bB = Bw + (size_t)(bn * 128 + srow) * K + schk * 8;

  int aoff[2][2], boff[2][4];
#pragma unroll
  for (int ks = 0; ks < 2; ++ks) {
#pragma unroll
    for (int f = 0; f < 2; ++f) {
      int arow = wr * 32 + f * 16 + l15;
      aoff[ks][f] = arow * 64 + (((ks * 4 + lq) ^ (arow & 7)) * 8);
    }
#pragma unroll
    for (int f = 0; f < 4; ++f) {
      int brow = wc * 64 + f * 16 + l15;
      boff[ks][f] = brow * 64 + (((ks * 4 + lq) ^ (brow & 7)) * 8);
    }
  }

  for (int kt = 0; kt < K; kt += 64) {
#pragma unroll
    for (int r = 0; r < 2; ++r)
      gld_lds16(aB + (size_t)(r * 32) * K + kt, As + r * 2048 + tid * 8);
#pragma unroll
    for (int r = 0; r < 4; ++r)
      gld_lds16(bB + (size_t)(r * 32) * K + kt, Bs + r * 2048 + tid * 8);
    __syncthreads();
#pragma unroll
    for (int ks = 0; ks < 2; ++ks) {
      bf16x8 af[2], bfr[4];
#pragma unroll
      for (int mf = 0; mf < 2; ++mf)
        af[mf] = *(const bf16x8*)&As[aoff[ks][mf]];
#pragma unroll
      for (int nf = 0; nf < 4; ++nf)
        bfr[nf] = *(const bf16x8*)&Bs[boff[ks][nf]];
#pragma unroll
      for (int mf = 0; mf < 2; ++mf)
#pragma unroll
        for (int nf = 0; nf < 4; ++nf)
          acc[mf][nf] = __builtin_amdgcn_mfma_f32_16x16x32_bf16(af[mf], bfr[nf], acc[mf][nf], 0, 0, 0);
    }
    __syncthreads();
  }
#pragma unroll
  for (int mf = 0; mf < 2; ++mf)
#pragma unroll
    for (int nf = 0; nf < 4; ++nf)
#pragma unroll
      for (int r = 0; r < 4; ++r) {
        int row = bm * 64 + wr * 32 + mf * 16 + lq * 4 + r;
        int col = bn * 128 + wc * 64 + nf * 16 + l15;
        C[(size_t)row * N + col] = acc[mf][nf][r];
      }
}

// ---------------- RoPE + extract heads ----------------
__global__ void rope_kernel(const float* __restrict__ Cq, bf16* __restrict__ qr,
                            bf16* __restrict__ kr, bf16* __restrict__ vt) {
  int idx = blockIdx.x * blockDim.x + threadIdx.x;  // (m, h, p)
  int p = idx & 31;
  int h = (idx >> 5) & 15;
  int m = idx >> 9;
  int s = m & (SEQ - 1);
  int b = m >> 11;
  const float* row = Cq + (size_t)m * H3 + h * 192;
  float q0 = row[2 * p], q1 = row[2 * p + 1];
  float k0 = row[64 + 2 * p], k1 = row[64 + 2 * p + 1];
  float v0 = row[128 + 2 * p], v1 = row[128 + 2 * p + 1];
  float invf = expf(-(float)p * (9.210340371976184f / 32.0f));  // 10000^(-2p/64)
  float fr = (float)s * invf;
  float sn, cs;
  sincosf(fr, &sn, &cs);
  const int bh = b * NHEAD + h;
  size_t o = ((size_t)bh * SEQ + s) * 64 + 2 * p;
  qr[o] = (bf16)((q0 * cs - q1 * sn) * 0.125f);
  qr[o + 1] = (bf16)((q1 * cs + q0 * sn) * 0.125f);
  kr[o] = (bf16)(k0 * cs - k1 * sn); kr[o + 1] = (bf16)(k1 * cs + k0 * sn);
  vt[((size_t)bh * 64 + 2 * p) * SEQ + s] = (bf16)v0;
  vt[((size_t)bh * 64 + 2 * p + 1) * SEQ + s] = (bf16)v1;
}

// ---------------- flash attention (round-9 verified structure) ----------------
// ROUND-10 deltas: bf16 mask reads; s_setprio(1) around both MFMA clusters (T5,
// measured +4-7% on attn with independent blocks, m191).
__global__ __launch_bounds__(256, 2)
void attn_kernel(const bf16* __restrict__ qr, const bf16* __restrict__ kr,
                 const bf16* __restrict__ vt, const bf16* __restrict__ maskb,
                 float* __restrict__ ctx) {
  __shared__ bf16 Kt[2][64 * 64];
  __shared__ bf16 Vt[2][64 * 64];
  __shared__ bf16 Pl[4][16 * 64];
  const int tid = threadIdx.x, lane = tid & 63, wid = tid >> 6;
  const int l15 = lane & 15, lq = lane >> 4;
  const int qt = blockIdx.x, bh = blockIdx.y;
  const int b = bh >> 4, hh = bh & 15;
  const size_t baseQ = ((size_t)bh * SEQ + qt * 64 + wid * 16) * 64;
  bf16x8 aq[2];
  aq[0] = *(const bf16x8*)&qr[baseQ + (size_t)l15 * 64 + 0 + lq * 8];
  aq[1] = *(const bf16x8*)&qr[baseQ + (size_t)l15 * 64 + 32 + lq * 8];
  float mrow[4], lrow[4];
  f32x4 oacc[4] = {};
#pragma unroll
  for (int r = 0; r < 4; ++r) { mrow[r] = -1e30f; lrow[r] = 0.0f; }
  const int srow = tid >> 3;
  const int schk = (tid & 7) ^ (srow & 7);
  const bf16* kBase = kr + ((size_t)bh * SEQ + srow) * 64 + schk * 8;
  const bf16* vBase = vt + ((size_t)bh * 64 + srow) * SEQ + schk * 8;

#define ASTAGE(bi_, kv_)                                                        \
  do {                                                                          \
    gld_lds16(kBase + (size_t)(kv_) * 64, &Kt[bi_][0] + tid * 8);               \
    gld_lds16(kBase + (size_t)((kv_) + 32) * 64, &Kt[bi_][0] + 2048 + tid * 8); \
    gld_lds16(vBase + (kv_), &Vt[bi_][0] + tid * 8);                            \
    gld_lds16(vBase + (size_t)32 * SEQ + (kv_), &Vt[bi_][0] + 2048 + tid * 8);  \
  } while (0)

  ASTAGE(0, 0);
  WAITVM0();
  BARRIER();
  for (int kv0 = 0; kv0 < SEQ; kv0 += 64) {
    const int cur = (kv0 >> 6) & 1;
    if (kv0 + 64 < SEQ) { ASTAGE(cur ^ 1, kv0 + 64); MEMFENCE(); }
    const bf16* kt = &Kt[cur][0];
    const bf16* vtl = &Vt[cur][0];
    f32x4 sacc[4] = {};
    __builtin_amdgcn_s_setprio(1);
#pragma unroll
    for (int k0 = 0; k0 < 2; ++k0) {
#pragma unroll
      for (int nf = 0; nf < 4; ++nf) {
        bf16x8 bk = *(const bf16x8*)&kt[(nf * 16 + l15) * 64 + (((k0 * 4 + lq) ^ (l15 & 7)) << 3)];
        sacc[nf] = __builtin_amdgcn_mfma_f32_16x16x32_bf16(aq[k0], bk, sacc[nf], 0, 0, 0);
      }
    }
    __builtin_amdgcn_s_setprio(0);
    const int qg0 = qt * 64 + wid * 16 + lq * 4;
#pragma unroll
    for (int nf = 0; nf < 4; ++nf) {
      int kvg = kv0 + nf * 16 + l15;
#pragma unroll
      for (int r = 0; r < 4; ++r)
        sacc[nf][r] += (float)maskb[(size_t)(qg0 + r) * SEQ + kvg];
    }
    float fac[4];
#pragma unroll
    for (int r = 0; r < 4; ++r) {
      float v = fmaxf(fmaxf(sacc[0][r], sacc[1][r]), fmaxf(sacc[2][r], sacc[3][r]));
      v = fmaxf(v, __shfl_xor(v, 1));
      v = fmaxf(v, __shfl_xor(v, 2));
      v = fmaxf(v, __shfl_xor(v, 4));
      v = fmaxf(v, __shfl_xor(v, 8));
      float mnew = fmaxf(mrow[r], v);
      fac[r] = __expf(mrow[r] - mnew);
      mrow[r] = mnew;
    }
    float rs[4] = {0, 0, 0, 0};
#pragma unroll
    for (int nf = 0; nf < 4; ++nf)
#pragma unroll
      for (int r = 0; r < 4; ++r) {
        float pv = __expf(sacc[nf][r] - mrow[r]);
        sacc[nf][r] = pv;
        rs[r] += pv;
      }
#pragma unroll
    for (int r = 0; r < 4; ++r) {
      float v = rs[r];
      v += __shfl_xor(v, 1); v += __shfl_xor(v, 2);
      v += __shfl_xor(v, 4); v += __shfl_xor(v, 8);
      lrow[r] = lrow[r] * fac[r] + v;
    }
#pragma unroll
    for (int nf = 0; nf < 4; ++nf)
#pragma unroll
      for (int r = 0; r < 4; ++r) {
        int qrow = lq * 4 + r;
        int col = nf * 16 + l15;
        Pl[wid][qrow * 64 + ((((col >> 3) ^ (qrow & 7))) << 3) + (col & 7)] = (bf16)sacc[nf][r];
      }
#pragma unroll
    for (int nf = 0; nf < 4; ++nf)
#pragma unroll
      for (int r = 0; r < 4; ++r)
        oacc[nf][r] *= fac[r];
    __builtin_amdgcn_s_setprio(1);
#pragma unroll
    for (int k0 = 0; k0 < 2; ++k0) {
      bf16x8 ap = *(const bf16x8*)&Pl[wid][l15 * 64 + (((k0 * 4 + lq) ^ (l15 & 7)) << 3)];
#pragma unroll
      for (int nf = 0; nf < 4; ++nf) {
        bf16x8 bv = *(const bf16x8*)&vtl[(nf * 16 + l15) * 64 + (((k0 * 4 + lq) ^ (l15 & 7)) << 3)];
        oacc[nf] = __builtin_amdgcn_mfma_f32_16x16x32_bf16(ap, bv, oacc[nf], 0, 0, 0);
      }
    }
    __builtin_amdgcn_s_setprio(0);
    WAITVM0();
    BARRIER();
  }
#undef ASTAGE
#pragma unroll
  for (int nf = 0; nf < 4; ++nf)
#pragma unroll
    for (int r = 0; r < 4; ++r) {
      int row = qt * 64 + wid * 16 + lq * 4 + r;
      int col = hh * 64 + nf * 16 + l15;
      ctx[((size_t)b * SEQ + row) * HID + col] = oacc[nf][r] / lrow[r];
    }
}

// ---------------- launch ----------------
extern "C" void kernel_launch(void* const* d_in, const int* in_sizes, int n_in,
                              void* d_out, int out_size, void* d_ws, size_t ws_size,
                              hipStream_t stream) {
  const float* qin    = (const float*)d_in[0];
  const float* kin    = (const float*)d_in[1];
  const float* vin    = (const float*)d_in[2];
  const float* mask   = (const float*)d_in[3];
  const float* qkv_bw = (const float*)d_in[4];
  const float* qkv_sw = (const float*)d_in[5];
  const float* qkv_sc = (const float*)d_in[6];
  const float* out_bw = (const float*)d_in[7];
  const float* out_sw = (const float*)d_in[8];
  const float* out_sc = (const float*)d_in[9];
  char* ws = (char*)d_ws;
  bf16* Wq  = (bf16*)(ws + WQ_OFF);
  bf16* Aq  = (bf16*)(ws + AQ_OFF);
  float* Cq = (float*)(ws + CQ_OFF);
  bf16* qr  = (bf16*)(ws + QR_OFF);
  bf16* kr  = (bf16*)(ws + KR_OFF);
  bf16* vt  = (bf16*)(ws + VB_OFF);
  float* ctx = (float*)(ws + CTX_OFF);
  bf16* A2  = (bf16*)(ws + A2_OFF);
  bf16* W2  = (bf16*)(ws + W2_OFF);
  bf16* mb  = (bf16*)(ws + MB_OFF);

  wprep_kernel<<<dim3(H3 / 256, H3), 256, 0, stream>>>(qkv_bw, qkv_sw, qkv_sc, Wq, H3);
  act_qkv_kernel<<<dim3(H3 / 256, MROWS), 256, 0, stream>>>(qin, kin, vin, Aq);
  gemm_kernel<<<dim3(H3 / 128, MROWS / 128), 256, 0, stream>>>(Aq, Wq, Cq, H3, K1DIM);
  maskprep_kernel<<<(SEQ * SEQ) / 1024, 256, 0, stream>>>(mask, mb);   // Wq dead now
  rope_kernel<<<(MROWS * NHEAD * 32) / 256, 256, 0, stream>>>(Cq, qr, kr, vt);
  attn_kernel<<<dim3(SEQ / 64, BATCH * NHEAD), 256, 0, stream>>>(qr, kr, vt, mb, ctx);
  act_out_kernel<<<dim3(HID / 256, MROWS), 256, 0, stream>>>(ctx, A2);
  wprep_kernel<<<dim3(HID / 256, HID), 256, 0, stream>>>(out_bw, out_sw, out_sc, W2, HID);
  gemm2_kernel<<<dim3(HID / 128, MROWS / 64), 256, 0, stream>>>(A2, W2, (float*)d_out, HID, K2DIM);
}